// Round 20
// baseline (1513.806 us; speedup 1.0000x reference)
//
#include <hip/hip_runtime.h>
#include <hip/hip_bf16.h>

// SwiGLU MLP: out = down( silu(x@Wg^T + bg) * (x@Wu^T + bu) ) + bd
// M=4096 tokens, H=4096, I=11008. fp32 in/out, bf16 MFMA compute.
// R20 = R19 + B-OPERANDS DIRECT TO REGISTERS (no LDS staging for weights):
// LDS-port arithmetic showed ~1000 cyc/tile of LDS traffic vs 620 cyc MFMA;
// B fragments have ZERO cross-wave reuse (wn partitions cols), so B-in-LDS was
// pure port overhead (write 32KB + read 64KB per tile). B now loads global->reg
// one tile ahead (ping-pong reg sets, 2x-unrolled loop), L3-resident bf16.
// A keeps LDS (real 4x wn-reuse): both halves staged in chunk1, order-pinned
// before B loads, ONE counted vmcnt(8)/tile retires A(t+1), B stays in flight.
// LDS 128->64 KiB. Epilogues/swizzle/XCD-map/cvt3/tail-fill: R19-verbatim.

#define M_TOK 4096
#define HID   4096
#define INT_  11008
#define NGU   1376          // 16 * 86 gu tiles (%8==0)
#define NCVT  160           // wd-convert tail blocks (96+160 = 256 exact fill)

typedef __attribute__((ext_vector_type(8))) short bf16x8;
typedef __attribute__((ext_vector_type(4))) float f32x4;

__device__ __forceinline__ unsigned short f2bf(float f) {
    union { float f; unsigned int u; } a; a.f = f;
    unsigned int u = a.u;
    u += 0x7fff + ((u >> 16) & 1);   // RNE
    return (unsigned short)(u >> 16);
}

// ---------------- combined fp32 -> bf16 convert: x, wg, wu in one launch -------
__global__ void cvt3(const float* __restrict__ x,  unsigned short* __restrict__ xb,
                     const float* __restrict__ wg, unsigned short* __restrict__ s1,
                     const float* __restrict__ wu, unsigned short* __restrict__ s2,
                     int n4x, int n4w) {
    const int total = n4x + 2 * n4w;
    const int stride = gridDim.x * blockDim.x;
    for (int i = blockIdx.x * blockDim.x + threadIdx.x; i < total; i += stride) {
        const float* src; unsigned short* dst; int j;
        if (i < n4x)            { j = i;             src = x;  dst = xb; }
        else if (i < n4x + n4w) { j = i - n4x;       src = wg; dst = s1; }
        else                    { j = i - n4x - n4w; src = wu; dst = s2; }
        float4 v = ((const float4*)src)[j];
        ushort4 o;
        o.x = f2bf(v.x); o.y = f2bf(v.y); o.z = f2bf(v.z); o.w = f2bf(v.w);
        ((ushort4*)dst)[j] = o;
    }
}

// ---------------- standalone fp32 -> bf16 (fallback path for wd) ---------------
__global__ void cvt_f32_bf16(const float* __restrict__ in, unsigned short* __restrict__ out, int n4) {
    int stride = gridDim.x * blockDim.x;
    for (int i = blockIdx.x * blockDim.x + threadIdx.x; i < n4; i += stride) {
        float4 v = ((const float4*)in)[i];
        ushort4 o;
        o.x = f2bf(v.x); o.y = f2bf(v.y); o.z = f2bf(v.z); o.w = f2bf(v.w);
        ((ushort4*)out)[i] = o;
    }
}

#define GLL(gsrc, ldst) \
    __builtin_amdgcn_global_load_lds( \
        (__attribute__((address_space(1))) void*)(gsrc), \
        (__attribute__((address_space(3))) void*)(ldst), 16, 0, 0)

#define VMC(n) asm volatile("s_waitcnt vmcnt(" #n ")" ::: "memory")
#define BARR __builtin_amdgcn_s_barrier()
#define PIN  __builtin_amdgcn_sched_barrier(0)

// ================= FUSED gate+up (+ wd-convert tail blocks) ====================
// x: M x K bf16 row-major (LDS-staged, 4x reuse); Wg,Wu: I x K bf16 row-major
// (direct global->reg, zero cross-wave reuse); out t: M x I bf16.
// Blocks [0,NGU): GEMM tile 256(M) x 128(I), BK=64, 8 waves (2Mx4N), 16x16x32.
// Blocks [NGU,NGU+NCVT): wd fp32->bf16 (grid-stride).
// LDS/buffer (shorts): A-half0 [0,8192) A-half1 [8192,16384). dbuf = 64 KiB.
// Within a row, 16B slot s stored at s^(r&7) (0 bank conflicts, R9-verified).
__global__ __launch_bounds__(512, 2)
void gemm_gu(const unsigned short* __restrict__ A,
             const unsigned short* __restrict__ Wg,
             const unsigned short* __restrict__ Wu,
             const float* __restrict__ bg,
             const float* __restrict__ bu,
             unsigned short* __restrict__ T,
             const float* __restrict__ wdSrc,
             unsigned short* __restrict__ wdDst,
             int M, int NI, int K) {
    __shared__ unsigned short lds[2 * 16384];   // 64 KiB (A only)

    const int tid  = threadIdx.x;

    // ---- wd-convert tail blocks ----
    if (blockIdx.x >= NGU) {
        const int c = blockIdx.x - NGU;
        const int n4w = (INT_ * HID) / 4;
        const float4* src = (const float4*)wdSrc;
        ushort4* dst = (ushort4*)wdDst;
        for (int u = c * 512 + tid; u < n4w; u += NCVT * 512) {
            float4 v = src[u];
            ushort4 o;
            o.x = f2bf(v.x); o.y = f2bf(v.y); o.z = f2bf(v.z); o.w = f2bf(v.w);
            dst[u] = o;
        }
        return;
    }

    const int lane = tid & 63;
    const int w    = tid >> 6;
    const int wm   = w >> 2;         // 0..1  (128 rows)
    const int wn   = w & 3;          // 0..3  (32 inter-cols)

    // XCD-aware bijective swizzle (NGU % 8 == 0)
    const int ntn = NI >> 7;                    // 86
    const int chunk = NGU >> 3;                 // 172
    const int sw = (blockIdx.x & 7) * chunk + (blockIdx.x >> 3);
    const int bm = sw / ntn, bn = sw % ntn;

    const unsigned short* Ag  = A  + (size_t)(bm * 256) * K;
    const unsigned short* Bgg = Wg + (size_t)(bn * 128) * K;
    const unsigned short* Bug = Wu + (size_t)(bn * 128) * K;

    // A staging source offsets (pre-swizzled; LDS dest linear)
    int offA[2][2];
#pragma unroll
    for (int i = 0; i < 2; ++i) {
        int sig = i * 512 + tid;
        int r   = sig >> 3;
        int s   = (sig & 7) ^ (r & 7);
#pragma unroll
        for (int h = 0; h < 2; ++h) {
            int grow = ((r >> 6) * 2 + h) * 64 + (r & 63);
            offA[h][i] = grow * K + s * 8;
        }
    }

    // A ds_read addressing (swizzled slots)
    const int rl = lane & 15;
    const int kg = lane >> 4;
    const int x  = rl & 7;
    const int aRow = (wm * 64 + rl) * 64;
    int slt[2];
#pragma unroll
    for (int ks = 0; ks < 2; ++ks) slt[ks] = ((ks * 4 + kg) ^ x) * 8;

    // B direct-load lane base: row (col) = wn*32 + fn*16 + rl; k-chunk kg*8
    const unsigned short* BgL = Bgg + (size_t)(wn * 32 + rl) * K + kg * 8;
    const unsigned short* BuL = Bug + (size_t)(wn * 32 + rl) * K + kg * 8;

    f32x4 accg[2][8], accu[2][8];
#pragma unroll
    for (int q = 0; q < 2; ++q)
#pragma unroll
        for (int f = 0; f < 8; ++f) {
            accg[q][f] = (f32x4){0.f, 0.f, 0.f, 0.f};
            accu[q][f] = (f32x4){0.f, 0.f, 0.f, 0.f};
        }

    const int NT = K >> 6;   // 64 (even)

#define STAGE_A(H, DST, SRC) \
    GLL((SRC) + offA[H][0], (DST) + (H) * 8192 + tid * 8); \
    GLL((SRC) + offA[H][1], (DST) + (H) * 8192 + 4096 + tid * 8)
#define RD_A(BUF, QM, DST) \
    { _Pragma("unroll") for (int ks = 0; ks < 2; ++ks) \
      _Pragma("unroll") for (int fm = 0; fm < 4; ++fm) \
        DST[ks * 4 + fm] = *(const bf16x8*)((BUF) + (QM) * 8192 + aRow + fm * 1024 + slt[ks]); }
#define LOADB(BASE, TS, DST) \
    { _Pragma("unroll") for (int ks = 0; ks < 2; ++ks) \
      _Pragma("unroll") for (int fn = 0; fn < 2; ++fn) \
        DST[ks * 2 + fn] = *(const bf16x8*)((BASE) + (size_t)fn * 16 * K + (size_t)(TS) * 64 + ks * 32); }
#define Q16(ACC, QM, AF, BF) \
    { _Pragma("unroll") for (int ks = 0; ks < 2; ++ks) \
      _Pragma("unroll") for (int fm = 0; fm < 4; ++fm) \
      _Pragma("unroll") for (int fn = 0; fn < 2; ++fn) \
        ACC[QM][fm * 2 + fn] = __builtin_amdgcn_mfma_f32_16x16x32_bf16( \
            AF[ks * 4 + fm], BF[ks * 2 + fn], ACC[QM][fm * 2 + fn], 0, 0, 0); }

    bf16x8 A0f[8], A1f[8], BgA[4], BuA[4], BgB[4], BuB[4];

    // ---- prologue: stage A(0) (4 GLL, pinned first), load B(0) regs ----
    STAGE_A(0, lds, Ag);
    STAGE_A(1, lds, Ag);
    PIN;                                // A GLLs precede B loads in VMEM order
    LOADB(BgL, 0, BgA);
    LOADB(BuL, 0, BuA);
    VMC(8);                             // retires A(0) GLLs; B(0) in flight
    BARR; PIN;

    // One tile: c1 {read A0 | stage A(t+1) both halves | load B(t+1) | 32 MFMA}
    //           c2 {read A1 | 32 MFMA | vmcnt(8) | barrier}
#define TILE_GU(T, BGC, BUC, BGN, BUN)                                          \
    {                                                                           \
        const unsigned short* bc = lds + ((T) & 1) * 16384;                     \
        unsigned short* sb = lds + (((T) + 1) & 1) * 16384;                     \
        const int ts = ((T) + 1 < NT) ? ((T) + 1) : (NT - 1);                   \
        const unsigned short* sA = Ag + (size_t)ts * 64;                        \
        RD_A(bc, 0, A0f);                                                       \
        STAGE_A(0, sb, sA);                                                     \
        STAGE_A(1, sb, sA);                                                     \
        PIN;                                                                    \
        LOADB(BgL, ts, BGN);                                                    \
        LOADB(BuL, ts, BUN);                                                    \
        Q16(accg, 0, A0f, BGC);                                                 \
        Q16(accu, 0, A0f, BUC);                                                 \
        BARR; PIN;                                                              \
        RD_A(bc, 1, A1f);                                                       \
        Q16(accg, 1, A1f, BGC);                                                 \
        Q16(accu, 1, A1f, BUC);                                                 \
        VMC(8);                         /* retires A(t+1); B(t+1) in flight */  \
        BARR; PIN;                                                              \
    }

    for (int t = 0; t < NT; t += 2) {
        TILE_GU(t,     BgA, BuA, BgB, BuB);
        TILE_GU(t + 1, BgB, BuB, BgA, BuA);
    }
#undef TILE_GU
#undef RD_A
#undef LOADB
#undef Q16
#undef STAGE_A

    // epilogue: C/D layout col=lane&15, row=(lane>>4)*4+j; t = silu(g)*u -> bf16
    const int rbase = bm * 256 + wm * 128 + (lane >> 4) * 4;
    const int cbase = bn * 128 + wn * 32 + (lane & 15);
#pragma unroll
    for (int qm = 0; qm < 2; ++qm)
#pragma unroll
        for (int fn = 0; fn < 2; ++fn) {
            const int col = cbase + fn * 16;
            const float bgv = bg[col];
            const float buv = bu[col];
#pragma unroll
            for (int fm = 0; fm < 4; ++fm) {
                const int rb = rbase + qm * 64 + fm * 16;
#pragma unroll
                for (int j = 0; j < 4; ++j) {
                    float g = accg[qm][fm * 2 + fn][j] + bgv;
                    float u = accu[qm][fm * 2 + fn][j] + buv;
                    float s = g / (1.f + __expf(-g)) * u;
                    T[(size_t)(rb + j) * (size_t)INT_ + col] = f2bf(s);
                }
            }
        }
}

// ================= down GEMM: out = t @ Wd^T + bd (fp32), B direct-to-reg ======
__global__ __launch_bounds__(512, 2)
void gemm_dn(const unsigned short* __restrict__ A,
             const unsigned short* __restrict__ B,
             const float* __restrict__ bias,
             float* __restrict__ C,
             int M, int N, int K) {
    __shared__ unsigned short lds[2 * 16384];   // 64 KiB (A only)

    const int tid  = threadIdx.x;
    const int lane = tid & 63;
    const int w    = tid >> 6;
    const int wm   = w >> 2;
    const int wn   = w & 3;

    const int ntn = N >> 8;
    const int chunk = gridDim.x >> 3;
    const int sw = (blockIdx.x & 7) * chunk + (blockIdx.x >> 3);
    const int bm = sw / ntn, bn = sw % ntn;

    const unsigned short* Ag = A + (size_t)(bm * 256) * K;
    const unsigned short* Bg = B + (size_t)(bn * 256) * K;

    int offA[2][2];
#pragma unroll
    for (int i = 0; i < 2; ++i) {
        int sig = i * 512 + tid;
        int r   = sig >> 3;
        int s   = (sig & 7) ^ (r & 7);
#pragma unroll
        for (int h = 0; h < 2; ++h) {
            int grow = ((r >> 6) * 2 + h) * 64 + (r & 63);
            offA[h][i] = grow * K + s * 8;
        }
    }

    const int rl = lane & 15;
    const int kg = lane >> 4;
    const int x  = rl & 7;
    const int aRow = (wm * 64 + rl) * 64;
    int slt[2];
#pragma unroll
    for (int ks = 0; ks < 2; ++ks) slt[ks] = ((ks * 4 + kg) ^ x) * 8;

    // B direct-load: col = wn*64 + qn*32 + fn*16 + rl (within bn*256 panel)
    const unsigned short* BL = Bg + (size_t)(wn * 64 + rl) * K + kg * 8;

    f32x4 acc[2][2][8];
#pragma unroll
    for (int qm = 0; qm < 2; ++qm)
#pragma unroll
        for (int qn = 0; qn < 2; ++qn)
#pragma unroll
            for (int f = 0; f < 8; ++f)
                acc[qm][qn][f] = (f32x4){0.f, 0.f, 0.f, 0.f};

    const int NT = K >> 6;   // 172 (even)

#define STAGE_A(H, DST, SRC) \
    GLL((SRC) + offA[H][0], (DST) + (H) * 8192 + tid * 8); \
    GLL((SRC) + offA[H][1], (DST) + (H) * 8192 + 4096 + tid * 8)
#define RD_A(BUF, QM, DST) \
    { _Pragma("unroll") for (int ks = 0; ks < 2; ++ks) \
      _Pragma("unroll") for (int fm = 0; fm < 4; ++fm) \
        DST[ks * 4 + fm] = *(const bf16x8*)((BUF) + (QM) * 8192 + aRow + fm * 1024 + slt[ks]); }
#define LOADB_DN(TS, D0, D1) \
    { _Pragma("unroll") for (int ks = 0; ks < 2; ++ks) \
      _Pragma("unroll") for (int fn = 0; fn < 2; ++fn) { \
        D0[ks * 2 + fn] = *(const bf16x8*)(BL + (size_t)(fn * 16) * K + (size_t)(TS) * 64 + ks * 32); \
        D1[ks * 2 + fn] = *(const bf16x8*)(BL + (size_t)(32 + fn * 16) * K + (size_t)(TS) * 64 + ks * 32); } }
#define Q16(QM, QN, AF, BF) \
    { _Pragma("unroll") for (int ks = 0; ks < 2; ++ks) \
      _Pragma("unroll") for (int fm = 0; fm < 4; ++fm) \
      _Pragma("unroll") for (int fn = 0; fn < 2; ++fn) \
        acc[QM][QN][fm * 2 + fn] = __builtin_amdgcn_mfma_f32_16x16x32_bf16( \
            AF[ks * 4 + fm], BF[ks * 2 + fn], acc[QM][QN][fm * 2 + fn], 0, 0, 0); }

    bf16x8 A0f[8], A1f[8], B0A[4], B1A[4], B0B[4], B1B[4];

    STAGE_A(0, lds, Ag);
    STAGE_A(1, lds, Ag);
    PIN;
    LOADB_DN(0, B0A, B1A);
    VMC(8);
    BARR; PIN;

#define TILE_DN(T, B0C, B1C, B0N, B1N)                                          \
    {                                                                           \
        const unsigned short* bc = lds + ((T) & 1) * 16384;                     \
        unsigned short* sb = lds + (((T) + 1) & 1) * 16384;                     \
        const int ts = ((T) + 1 < NT) ? ((T) + 1) : (NT - 1);                   \
        const unsigned short* sA = Ag + (size_t)ts * 64;                        \
        RD_A(bc, 0, A0f);                                                       \
        STAGE_A(0, sb, sA);                                                     \
        STAGE_A(1, sb, sA);                                                     \
        PIN;                                                                    \
        LOADB_DN(ts, B0N, B1N);                                                 \
        Q16(0, 0, A0f, B0C);                                                    \
        Q16(0, 1, A0f, B1C);                                                    \
        BARR; PIN;                                                              \
        RD_A(bc, 1, A1f);                                                       \
        Q16(1, 1, A1f, B1C);                                                    \
        Q16(1, 0, A1f, B0C);                                                    \
        VMC(8);                                                                 \
        BARR; PIN;                                                              \
    }

    for (int t = 0; t < NT; t += 2) {
        TILE_DN(t,     B0A, B1A, B0B, B1B);
        TILE_DN(t + 1, B0B, B1B, B0A, B1A);
    }
#undef TILE_DN
#undef RD_A
#undef LOADB_DN
#undef Q16
#undef STAGE_A

    const int rbase = bm * 256 + wm * 128 + (lane >> 4) * 4;
    const int cbase = bn * 256 + wn * 64 + (lane & 15);
#pragma unroll
    for (int qm = 0; qm < 2; ++qm)
#pragma unroll
        for (int qn = 0; qn < 2; ++qn)
#pragma unroll
            for (int fn = 0; fn < 2; ++fn) {
                const int col = cbase + qn * 32 + fn * 16;
                const float bv = bias[col];
#pragma unroll
                for (int fm = 0; fm < 4; ++fm) {
                    const int rb = rbase + qm * 64 + fm * 16;
#pragma unroll
                    for (int j = 0; j < 4; ++j)
                        C[(size_t)(rb + j) * (size_t)N + col] = acc[qm][qn][fm * 2 + fn][j] + bv;
                }
            }
}

// ---------------- launcher ----------------
extern "C" void kernel_launch(void* const* d_in, const int* in_sizes, int n_in,
                              void* d_out, int out_size, void* d_ws, size_t ws_size,
                              hipStream_t stream) {
    const float* x  = (const float*)d_in[0];   // (2,2048,4096)
    const float* wg = (const float*)d_in[1];   // (11008,4096)
    const float* bg = (const float*)d_in[2];
    const float* wu = (const float*)d_in[3];
    const float* bu = (const float*)d_in[4];
    const float* wd = (const float*)d_in[5];   // (4096,11008)
    const float* bd = (const float*)d_in[6];

    const size_t NX = (size_t)M_TOK * HID;     // 16,777,216
    const size_t NW = (size_t)INT_ * HID;      // 45,088,768

    unsigned short* ws = (unsigned short*)d_ws;
    unsigned short* Xb = ws;                   // x bf16
    unsigned short* S1 = Xb + NX;              // Wg bf16 (fallback: -> Wd later)
    unsigned short* S2 = S1 + NW;              // Wu bf16
    unsigned short* S3 = S2 + NW;              // t = silu(g)*u bf16
    unsigned short* S4 = S3 + NW;              // Wd bf16 (fused path only)

    const bool fused = ws_size >= (NX + 4 * NW) * 2;   // 394,264,576 B

    dim3 blk512(512);
    dim3 blk256(256);

    cvt3<<<2048, blk256, 0, stream>>>(x, Xb, wg, S1, wu, S2,
                                      (int)(NX / 4), (int)(NW / 4));

    if (fused) {
        gemm_gu<<<dim3(NGU + NCVT), blk512, 0, stream>>>(Xb, S1, S2, bg, bu, S3,
                                                         wd, S4, M_TOK, INT_, HID);
        gemm_dn<<<dim3(16 * 16), blk512, 0, stream>>>(S3, S4, bd, (float*)d_out,
                                                      M_TOK, HID, INT_);
    } else {
        gemm_gu<<<dim3(NGU), blk512, 0, stream>>>(Xb, S1, S2, bg, bu, S3,
                                                  (const float*)nullptr,
                                                  (unsigned short*)nullptr,
                                                  M_TOK, INT_, HID);
        cvt_f32_bf16<<<2048, blk256, 0, stream>>>(wd, S1, (int)(NW / 4));
        gemm_dn<<<dim3(16 * 16), blk512, 0, stream>>>(S3, S1, bd, (float*)d_out,
                                                      M_TOK, HID, INT_);
    }
}